// Round 23
// baseline (119.687 us; speedup 1.0000x reference)
//
#include <hip/hip_runtime.h>
#include <hip/hip_bf16.h>

// ProcessNeurons: B=8, S=2048, K_IN=128, D_MODEL=1024, N_INPUT=256,
// N_PROC=1024, K_PROC=256. Inputs fp32 (+int32 idx), output fp32.
// R21/R22: bank-conflict fixes neutral -> conflicts off critical path;
// k4_fused is staging-issue/latency bound at 4 blocks/CU. R23: k4 s-tile
// 128->64 (LDS 33->25KB -> 6 blocks/CU, grid 2048) — the R10/R15 lever.
// Same accumulation order -> bit-identical output.
#define NB    8
#define NS    2048
#define NKIN  128
#define NPROC 1024
#define NIN   256
#define NDM   1024
#define NKP   256
#define NSEG  32     // k1 S-segments (NS/64)

typedef unsigned short u16;
typedef unsigned int   u32;
typedef __attribute__((ext_vector_type(4))) u16   u16x4;
typedef __attribute__((ext_vector_type(8))) u16   u16x8;
typedef __attribute__((ext_vector_type(4))) float f32x4;
typedef __attribute__((ext_vector_type(8))) short bf16x8;   // MFMA A/B frag
typedef __attribute__((ext_vector_type(4))) float f32x4v;   // MFMA C/D frag

__device__ __forceinline__ float bf2f(u16 u) {
    union { u32 i; float f; } v; v.i = ((u32)u) << 16; return v.f;
}
__device__ __forceinline__ u16 f2bf(float f) {
    u32 x = __float_as_uint(f);
    u32 r = (x + 0x7FFFu + ((x >> 16) & 1u)) >> 16;   // RNE
    return (u16)r;
}
// A&S 7.1.26 erf approximation, |err| <= 1.5e-7 abs (R14-proven).
__device__ __forceinline__ float gelu_fast(float x) {
    float y  = fabsf(x) * 0.70710678118654752f;        // |x|/sqrt(2)
    float t  = __builtin_amdgcn_rcpf(fmaf(0.3275911f, y, 1.0f));
    float p  = t * fmaf(t, fmaf(t, fmaf(t, fmaf(t, 1.061405429f,
               -1.453152027f), 1.421413741f), -0.284496736f), 0.254829592f);
    float e  = __expf(-y * y);
    float er = fmaf(-p, e, 1.0f);                      // erf(|x|/sqrt(2))
    float s  = copysignf(er, x);
    return 0.5f * x * (1.0f + s);
}
__device__ __forceinline__ int clampi(int v, int hi) {
    return v < 0 ? 0 : (v > hi ? hi : v);
}

// ---------------------------------------------------------------------------
// K0m (merged): blocks [0,1024): split A -> AHi/ALo.
//               blocks [1024,1088): gather+split W -> WgHi/WgLo.
// ---------------------------------------------------------------------------
__global__ __launch_bounds__(256) void k0_merged(
        const float* __restrict__ A, const float* __restrict__ W,
        const int* __restrict__ idx, u16* __restrict__ AHi,
        u16* __restrict__ ALo, u16* __restrict__ WgHi,
        u16* __restrict__ WgLo) {
    const int blk = blockIdx.x;
    const int tid = threadIdx.x;
    if (blk < 1024) {                       // ---- splitA ----
        size_t i = ((size_t)blk * 256 + tid) * 8;
        f32x4 a = *(const f32x4*)&A[i];
        f32x4 c = *(const f32x4*)&A[i + 4];
        u16x8 h, l;
        #pragma unroll
        for (int j = 0; j < 4; ++j) {
            u16 hj = f2bf(a[j]); h[j] = hj;     l[j]     = f2bf(a[j] - bf2f(hj));
            u16 hk = f2bf(c[j]); h[j + 4] = hk; l[j + 4] = f2bf(c[j] - bf2f(hk));
        }
        *(u16x8*)&AHi[i] = h;
        *(u16x8*)&ALo[i] = l;
    } else {                                // ---- W prep ----
        const int q  = blk - 1024;          // 0..63
        const int b  = q >> 3;
        const int p0 = (q & 7) * 128;
        __shared__ int idxs[NKIN];
        if (tid < NKIN) idxs[tid] = clampi(idx[b * NKIN + tid], NIN - 1);
        __syncthreads();
        for (int e = tid; e < 128 * NKIN; e += 256) {
            int p = p0 + (e >> 7), k = e & 127;
            float x  = W[p * NIN + idxs[k]];
            u16 hi   = f2bf(x);
            u16 lo   = f2bf(x - bf2f(hi));
            size_t o = (size_t)(b * NPROC + p) * NKIN + k;
            WgHi[o] = hi;
            WgLo[o] = lo;
        }
    }
}

// ---------------------------------------------------------------------------
// K1 (split MFMA + acts_t store, BK=32 four-phase): scores + gelu acts.
// acc = Ahi*Whi + Ahi*Wlo + Alo*Whi. 64x64 tile, 4 waves. LDS pool 20.5KB.
// grid 4096, block 256. (R16-proven, unchanged)
// ---------------------------------------------------------------------------
__global__ __launch_bounds__(256) void k1_scores(
        const u16* __restrict__ AHi, const u16* __restrict__ ALo,
        const u16* __restrict__ WgHi, const u16* __restrict__ WgLo,
        float* __restrict__ scores, u16* __restrict__ acts_t) {
    const int lin  = blockIdx.x;
    const int b    = lin & 7;        // XCD via round-robin dispatch
    const int q    = lin >> 3;       // 0..511
    const int pblk = q & 15;         // 0..15
    const int sblk = q >> 4;         // 0..31
    const int p0 = pblk * 64, s0 = sblk * 64;
    const int tid  = threadIdx.x;
    const int lane = tid & 63;
    const int wid  = tid >> 6;
    const int wr   = wid >> 1;       // s quadrant
    const int wc   = wid & 1;        // p quadrant
    const int lr   = lane & 15;
    const int kr   = lane >> 4;

    __shared__ u16  pool[4 * 64 * 40];
    __shared__ float red[2][64];
    char* const pb = (char*)pool;

    f32x4v acc[2][2] = {};

    for (int kc = 0; kc < 4; ++kc) {             // four BK=32 phases
        __syncthreads();
        {   // stage A chunk
            int r = tid >> 2, g = tid & 3;
            size_t src = (size_t)(b * NS + s0 + r) * NKIN + kc * 32 + g * 8;
            u32 off = (u32)r * 80 + (u32)g * 16;
            *(u16x8*)(pb + off)         = *(const u16x8*)&AHi[src];
            *(u16x8*)(pb + 5120 + off)  = *(const u16x8*)&ALo[src];
        }
        {   // stage W chunk
            int pp = tid >> 2, g = tid & 3;
            size_t src = (size_t)(b * NPROC + p0 + pp) * NKIN + kc * 32 + g * 8;
            u32 off = (u32)pp * 80 + (u32)g * 16;
            *(u16x8*)(pb + 10240 + off) = *(const u16x8*)&WgHi[src];
            *(u16x8*)(pb + 15360 + off) = *(const u16x8*)&WgLo[src];
        }
        __syncthreads();

        const u32 kb = (u32)kr * 16;
        bf16x8 ah[2], al[2], wh[2], wl[2];
        #pragma unroll
        for (int m = 0; m < 2; ++m) {
            u32 row = (u32)(wr * 32 + m * 16 + lr);
            u32 off = row * 80 + kb;
            ah[m] = *(const bf16x8*)(pb + off);
            al[m] = *(const bf16x8*)(pb + 5120 + off);
        }
        #pragma unroll
        for (int n = 0; n < 2; ++n) {
            u32 col = (u32)(wc * 32 + n * 16 + lr);
            u32 off = col * 80 + kb;
            wh[n] = *(const bf16x8*)(pb + 10240 + off);
            wl[n] = *(const bf16x8*)(pb + 15360 + off);
        }
        #pragma unroll
        for (int m = 0; m < 2; ++m)
            #pragma unroll
            for (int n = 0; n < 2; ++n) {
                acc[m][n] = __builtin_amdgcn_mfma_f32_16x16x32_bf16(
                    ah[m], wh[n], acc[m][n], 0, 0, 0);
                acc[m][n] = __builtin_amdgcn_mfma_f32_16x16x32_bf16(
                    ah[m], wl[n], acc[m][n], 0, 0, 0);
                acc[m][n] = __builtin_amdgcn_mfma_f32_16x16x32_bf16(
                    al[m], wh[n], acc[m][n], 0, 0, 0);
            }
    }

    // ---- epilogue ----
    __syncthreads();   // pool dead -> actsT[p 64][s 64] swizzled
    float colsum[2] = {0.f, 0.f};
    #pragma unroll
    for (int n = 0; n < 2; ++n)
        #pragma unroll
        for (int m = 0; m < 2; ++m)
            #pragma unroll
            for (int j = 0; j < 4; ++j) {
                float g = gelu_fast(acc[m][n][j]);
                colsum[n] += g;
                if (acts_t) {
                    u32 p = (u32)(wc * 32 + n * 16 + lr);
                    u32 s = (u32)(wr * 32 + m * 16 + kr * 4 + j);
                    u32 off = p * 128 + ((((s >> 3) ^ (p & 7)) & 7) << 4)
                              + (s & 7) * 2;
                    *(u16*)(pb + off) = f2bf(g);
                }
            }
    #pragma unroll
    for (int n = 0; n < 2; ++n) {
        colsum[n] += __shfl_xor(colsum[n], 16, 64);
        colsum[n] += __shfl_xor(colsum[n], 32, 64);
    }
    if (lane < 16) {
        #pragma unroll
        for (int n = 0; n < 2; ++n)
            red[wr][wc * 32 + n * 16 + lane] = colsum[n];
    }
    __syncthreads();
    if (tid < 64)
        scores[(size_t)(sblk * NB + b) * NPROC + p0 + tid] =
            red[0][tid] + red[1][tid];
    if (acts_t) {
        #pragma unroll
        for (int e = tid; e < 512; e += 256) {   // 64 p-rows x 8 s-groups
            int r = e >> 3, g = e & 7;
            u32 off = (u32)r * 128 + ((((u32)g ^ ((u32)r & 7)) & 7) << 4);
            *(u16x8*)&acts_t[(size_t)(b * NPROC + p0 + r) * NS + s0 + g * 8] =
                *(const u16x8*)(pb + off);
        }
    }
}

// ---------------------------------------------------------------------------
// K2: top-k by stable rank count (value desc, index asc == lax.top_k).
// ---------------------------------------------------------------------------
__global__ __launch_bounds__(256) void k2_topk(
        const float* __restrict__ scores, int* __restrict__ topk) {
    const int b  = blockIdx.x;
    const int pc = blockIdx.y;
    __shared__ float sc[NPROC];
    #pragma unroll
    for (int q = 0; q < 4; ++q) {
        int p = q * 256 + threadIdx.x;
        float v = 0.f;
        #pragma unroll
        for (int seg = 0; seg < NSEG; ++seg)
            v += scores[(size_t)(seg * NB + b) * NPROC + p];
        sc[p] = v;
    }
    __syncthreads();
    const int p = pc * 256 + threadIdx.x;
    const float v = sc[p];
    int rank = 0;
    #pragma unroll 4
    for (int jj = 0; jj < NPROC / 4; ++jj) {
        f32x4 s4 = *(const f32x4*)&sc[jj * 4];
        #pragma unroll
        for (int c = 0; c < 4; ++c) {
            int j = jj * 4 + c;
            rank += (s4[c] > v) || (s4[c] == v && j < p);
        }
    }
    if (rank < NKP) topk[b * NKP + rank] = p;
}

// ---------------------------------------------------------------------------
// K4f (fused gather+GEMM, R23 64s x 128d tile): out[b,s,d] =
// sum_c acts_t[b,tloc[c],s]*PO[tloc[c],d]. LDS 25KB -> 6 blocks/CU.
// Same k-order/fragments as R22 -> bit-identical. grid 2048, block 256.
// ---------------------------------------------------------------------------
__global__ __launch_bounds__(256) void k4_fused(
        const u16* __restrict__ acts_t, const float* __restrict__ PO,
        const int* __restrict__ topk, float* __restrict__ out) {
    const int lin  = blockIdx.x;
    const int b    = lin & 7;
    const int q    = lin >> 3;       // 0..255
    const int dblk = q & 7;
    const int sblk = q >> 3;         // 0..31
    const int d0 = dblk * 128, s0 = sblk * 64;
    const int tid  = threadIdx.x;
    const int lane = tid & 63;
    const int wid  = tid >> 6;
    const int wr   = wid >> 1;       // s half (0/1, 32 rows each)
    const int wc   = wid & 1;        // d half (0/1, 64 cols each)

    __shared__ int tloc[NKP];
    __shared__ u16 Alds[64 * 64];    // [s 64][c 64], 128B rows, SW4 swizzle
    __shared__ u16 Blds[128 * 64];   // [d 128][k 64], (n&7) swizzle

    tloc[tid] = clampi(topk[b * NKP + tid], NPROC - 1);

    f32x4v acc[2][4] = {};

    for (int k0 = 0; k0 < NKP; k0 += 64) {
        __syncthreads();
        // ---- A: gather 64 selected acts_t rows x 64 s (512 u16x8 tasks) ----
        for (int e = tid; e < 512; e += 256) {
            int r = e & 63, g = e >> 6;   // c-row, s-group (0..7)
            u16x8 v = *(const u16x8*)&acts_t[
                (size_t)(b * NPROC + tloc[k0 + r]) * NS + s0 + g * 8];
            #pragma unroll
            for (int j = 0; j < 8; ++j) {
                u32 s = (u32)(g * 8 + j);
                u32 sw = (s & 7) ^ ((s >> 3) & 7);
                u32 off = s * 128 + (((((u32)r >> 3) ^ sw) & 7) << 4)
                          + ((u32)r & 7) * 2;
                *(u16*)((char*)Alds + off) = v[j];
            }
        }
        // ---- B: gathered PO rows (R22 flip: kp spans lanes) ----
        for (int e = tid; e < 1024; e += 256) {
            int kp = e & 31, cg = e >> 5;
            f32x4 p0v = *(const f32x4*)&PO[(size_t)tloc[k0 + kp * 2]     * NDM + d0 + cg * 4];
            f32x4 p1v = *(const f32x4*)&PO[(size_t)tloc[k0 + kp * 2 + 1] * NDM + d0 + cg * 4];
            #pragma unroll
            for (int j = 0; j < 4; ++j) {
                int n = cg * 4 + j;
                u32 pack = (u32)f2bf(p0v[j]) | ((u32)f2bf(p1v[j]) << 16);
                u32 byteoff = (u32)n * 128 + (((u32)kp * 4) ^ (((u32)n & 7) << 4));
                *(u32*)((char*)Blds + byteoff) = pack;
            }
        }
        __syncthreads();

        #pragma unroll
        for (int kk = 0; kk < 2; ++kk) {
            const u32 slotk  = (u32)(kk * 4 + (lane >> 4));
            const u32 kbase2 = (u32)(kk * 64 + (lane >> 4) * 16);
            bf16x8 afrag[2], bfrag[4];
            #pragma unroll
            for (int m = 0; m < 2; ++m) {
                u32 row = (u32)(wr * 32 + m * 16 + (lane & 15));   // s
                u32 sw  = (row & 7) ^ ((row >> 3) & 7);
                u32 byteoff = row * 128 + (((slotk ^ sw) & 7) << 4);
                afrag[m] = *(const bf16x8*)((const char*)Alds + byteoff);
            }
            #pragma unroll
            for (int n = 0; n < 4; ++n) {
                u32 col = (u32)(wc * 64 + n * 16 + (lane & 15));
                u32 byteoff = col * 128 + (kbase2 ^ ((col & 7) << 4));
                bfrag[n] = *(const bf16x8*)((const char*)Blds + byteoff);
            }
            #pragma unroll
            for (int m = 0; m < 2; ++m)
                #pragma unroll
                for (int n = 0; n < 4; ++n)
                    acc[m][n] = __builtin_amdgcn_mfma_f32_16x16x32_bf16(
                        afrag[m], bfrag[n], acc[m][n], 0, 0, 0);
        }
    }

    #pragma unroll
    for (int m = 0; m < 2; ++m) {
        const int rbase = s0 + wr * 32 + m * 16 + (lane >> 4) * 4;
        #pragma unroll
        for (int n = 0; n < 4; ++n) {
            const int col = d0 + wc * 64 + n * 16 + (lane & 15);
            #pragma unroll
            for (int j = 0; j < 4; ++j)
                out[(size_t)(b * NS + rbase + j) * NDM + col] = acc[m][n][j];
        }
    }
}

// ---------------------------------------------------------------------------
// K3 (fallback, small ws): prefetch-all MFMA recompute -> sel. grid 1024.
// ---------------------------------------------------------------------------
__global__ __launch_bounds__(256) void k3_selacts(
        const u16* __restrict__ AHi, const u16* __restrict__ WgHi,
        const int* __restrict__ topk, u16* __restrict__ sel) {
    const int lin  = blockIdx.x;
    const int b    = lin & 7;
    const int q    = lin >> 3;
    const int cblk = q & 3;
    const int sblk = q >> 2;
    const int c0g = cblk * 64, s0 = sblk * 64;
    const int tid  = threadIdx.x;
    const int lane = tid & 63;
    const int wid  = tid >> 6;
    const int wr   = wid >> 1;
    const int wc   = wid & 1;
    const int lr   = lane & 15;
    const int kr   = lane >> 4;

    __shared__ int tcol[64];
    if (tid < 64) tcol[tid] = clampi(topk[b * NKP + c0g + tid], NPROC - 1);
    __syncthreads();

    const u16* ap[2];
    const u16* wp[2];
    #pragma unroll
    for (int m = 0; m < 2; ++m)
        ap[m] = &AHi[(size_t)(b * NS + s0 + wr * 32 + m * 16 + lr) * NKIN + kr * 8];
    #pragma unroll
    for (int n = 0; n < 2; ++n)
        wp[n] = &WgHi[(size_t)(b * NPROC + tcol[wc * 32 + n * 16 + lr]) * NKIN + kr * 8];

    bf16x8 af[2][4], bf[2][4];
    #pragma unroll
    for (int ks = 0; ks < 4; ++ks) {
        #pragma unroll
        for (int m = 0; m < 2; ++m) af[m][ks] = *(const bf16x8*)(ap[m] + ks * 32);
        #pragma unroll
        for (int n = 0; n < 2; ++n) bf[n][ks] = *(const bf16x8*)(wp[n] + ks * 32);
    }

    f32x4v acc[2][2] = {};
    #pragma unroll
    for (int ks = 0; ks < 4; ++ks)
        #pragma unroll
        for (int m = 0; m < 2; ++m)
            #pragma unroll
            for (int n = 0; n < 2; ++n)
                acc[m][n] = __builtin_amdgcn_mfma_f32_16x16x32_bf16(
                    af[m][ks], bf[n][ks], acc[m][n], 0, 0, 0);

    #pragma unroll
    for (int m = 0; m < 2; ++m) {
        const int rbase = s0 + wr * 32 + m * 16 + (lane >> 4) * 4;
        #pragma unroll
        for (int n = 0; n < 2; ++n) {
            const int col = c0g + wc * 32 + n * 16 + lr;
            #pragma unroll
            for (int j = 0; j < 4; ++j)
                sel[(size_t)(b * NS + rbase + j) * NKP + col] =
                    f2bf(gelu_fast(acc[m][n][j]));
        }
    }
}

// ---------------------------------------------------------------------------
// K4 (fallback, small ws): sel @ gathered-PO. grid 1024.
// ---------------------------------------------------------------------------
__global__ __launch_bounds__(256) void k4_mfma(
        const u16* __restrict__ sel, const float* __restrict__ PO,
        const int* __restrict__ topk, float* __restrict__ out) {
    const int lin  = blockIdx.x;
    const int b    = lin & 7;
    const int q    = lin >> 3;
    const int dblk = q & 7;
    const int sblk = q >> 3;
    const int d0 = dblk * 128, s0 = sblk * 128;
    const int tid  = threadIdx.x;
    const int lane = tid & 63;
    const int wid  = tid >> 6;
    const int wr   = wid >> 1;
    const int wc   = wid & 1;

    __shared__ int tloc[NKP];
    __shared__ u16 Alds[128 * 64];
    __shared__ u16 Blds[128 * 64];

    tloc[tid] = clampi(topk[b * NKP + tid], NPROC - 1);

    f32x4v acc[4][4] = {};

    for (int k0 = 0; k0 < NKP; k0 += 64) {
        __syncthreads();
        for (int e = tid; e < 1024; e += 256) {
            int r = e >> 3, g = e & 7;
            u16x8 v = *(const u16x8*)&sel[(size_t)(b * NS + s0 + r) * NKP + k0 + g * 8];
            int slot = g ^ (r & 7);
            *(u16x8*)&Alds[r * 64 + slot * 8] = v;
        }
        for (int e = tid; e < 1024; e += 256) {
            int kp = e & 31, cg = e >> 5;
            f32x4 p0v = *(const f32x4*)&PO[(size_t)tloc[k0 + kp * 2]     * NDM + d0 + cg * 4];
            f32x4 p1v = *(const f32x4*)&PO[(size_t)tloc[k0 + kp * 2 + 1] * NDM + d0 + cg * 4];
            #pragma unroll
            for (int j = 0; j < 4; ++j) {
                int n = cg * 4 + j;
                u32 pack = (u32)f2bf(p0v[j]) | ((u32)f2bf(p1v[j]) << 16);
                u32 byteoff = (u32)n * 128 + (((u32)kp * 4) ^ (((u32)n & 7) << 4));
                *(u32*)((char*)Blds + byteoff) = pack;
            }
        }
        __syncthreads();

        #pragma unroll
        for (int kk = 0; kk < 2; ++kk) {
            const u32 kbase2 = (u32)(kk * 64 + (lane >> 4) * 16);
            bf16x8 afrag[4], bfrag[4];
            #pragma unroll
            for (int m = 0; m < 4; ++m) {
                u32 row = (u32)(wr * 64 + m * 16 + (lane & 15));
                u32 byteoff = row * 128 + (kbase2 ^ ((row & 7) << 4));
                afrag[m] = *(const bf16x8*)((const char*)Alds + byteoff);
            }
            #pragma unroll
            for (int n = 0; n < 4; ++n) {
                u32 col = (u32)(wc * 64 + n * 16 + (lane & 15));
                u32 byteoff = col * 128 + (kbase2 ^ ((col & 7) << 4));
                bfrag[n] = *(const bf16x8*)((const char*)Blds + byteoff);
            }
            #pragma unroll
            for (int m = 0; m < 4; ++m)
                #pragma unroll
                for (int n = 0; n < 4; ++n)
                    acc[m][n] = __builtin_amdgcn_mfma_f32_16x16x32_bf16(
                        afrag[m], bfrag[n], acc[m][n], 0, 0, 0);
        }
    }

    #pragma unroll
    for (int m = 0; m < 4; ++m) {
        const int rbase = s0 + wr * 64 + m * 16 + (lane >> 4) * 4;
        #pragma unroll
        for (int n = 0; n < 4; ++n) {
            const int col = d0 + wc * 64 + n * 16 + (lane & 15);
            #pragma unroll
            for (int j = 0; j < 4; ++j)
                out[(size_t)(b * NS + rbase + j) * NDM + col] = acc[m][n][j];
        }
    }
}

// ---------------------------------------------------------------------------
extern "C" void kernel_launch(void* const* d_in, const int* in_sizes, int n_in,
                              void* d_out, int out_size, void* d_ws, size_t ws_size,
                              hipStream_t stream) {
    (void)in_sizes; (void)n_in; (void)out_size;
    const float* A   = (const float*)d_in[0];   // (B,S,K_IN) fp32
    const float* W   = (const float*)d_in[1];   // (N_PROC,N_INPUT) fp32
    const float* PO  = (const float*)d_in[2];   // (N_PROC,D_MODEL) fp32
    const int*   idx = (const int*)d_in[3];     // (B,K_IN) int32
    float* out = (float*)d_out;                 // (B,S,D_MODEL) fp32

    // ws: sel 8388608 | scores 1048576 | topk 8192 | WgHi 2097152 |
    //     WgLo 2097152 | AHi 4194304 | ALo 4194304 | acts_t 33554432
    char* w = (char*)d_ws;
    u16*   sel    = (u16*)w;
    float* scores = (float*)(w + (size_t)8388608);
    int*   topk   = (int*)(w + (size_t)9437184);
    u16*   WgHi   = (u16*)(w + (size_t)9445376);
    u16*   WgLo   = (u16*)(w + (size_t)11542528);
    u16*   AHi    = (u16*)(w + (size_t)13639680);
    u16*   ALo    = (u16*)(w + (size_t)17833984);
    u16*   acts_t = (u16*)(w + (size_t)22028288);   // [B][NPROC][NS] bf16
    const bool big = ws_size >= (size_t)22028288 + 33554432;   // 53 MB

    k0_merged<<<1024 + 64, 256, 0, stream>>>(A, W, idx, AHi, ALo, WgHi, WgLo);
    k1_scores<<<4096, 256, 0, stream>>>(AHi, ALo, WgHi, WgLo, scores,
                                        big ? acts_t : (u16*)nullptr);
    k2_topk<<<dim3(NB, 4), 256, 0, stream>>>(scores, topk);
    if (big) {
        k4_fused<<<2048, 256, 0, stream>>>(acts_t, PO, topk, out);
    } else {
        k3_selacts<<<1024, 256, 0, stream>>>(AHi, WgHi, topk, sel);
        k4_mfma<<<1024, 256, 0, stream>>>(sel, PO, topk, out);
    }
}

// Round 24
// 108.366 us; speedup vs baseline: 1.1045x; 1.1045x over previous
//
#include <hip/hip_runtime.h>
#include <hip/hip_bf16.h>

// ProcessNeurons: B=8, S=2048, K_IN=128, D_MODEL=1024, N_INPUT=256,
// N_PROC=1024, K_PROC=256. Inputs fp32 (+int32 idx), output fp32.
// R24 = R22 verbatim (best measured: 108.7us). R23's s-tile halving
// regressed (B-staging doubled; staging issue-bound). Plateau mapped:
// R20 108.97 / R21 108.71 / R22 108.76. Final configuration.
#define NB    8
#define NS    2048
#define NKIN  128
#define NPROC 1024
#define NIN   256
#define NDM   1024
#define NKP   256
#define NSEG  32     // k1 S-segments (NS/64)

typedef unsigned short u16;
typedef unsigned int   u32;
typedef __attribute__((ext_vector_type(4))) u16   u16x4;
typedef __attribute__((ext_vector_type(8))) u16   u16x8;
typedef __attribute__((ext_vector_type(4))) float f32x4;
typedef __attribute__((ext_vector_type(8))) short bf16x8;   // MFMA A/B frag
typedef __attribute__((ext_vector_type(4))) float f32x4v;   // MFMA C/D frag

__device__ __forceinline__ float bf2f(u16 u) {
    union { u32 i; float f; } v; v.i = ((u32)u) << 16; return v.f;
}
__device__ __forceinline__ u16 f2bf(float f) {
    u32 x = __float_as_uint(f);
    u32 r = (x + 0x7FFFu + ((x >> 16) & 1u)) >> 16;   // RNE
    return (u16)r;
}
// A&S 7.1.26 erf approximation, |err| <= 1.5e-7 abs (R14-proven).
__device__ __forceinline__ float gelu_fast(float x) {
    float y  = fabsf(x) * 0.70710678118654752f;        // |x|/sqrt(2)
    float t  = __builtin_amdgcn_rcpf(fmaf(0.3275911f, y, 1.0f));
    float p  = t * fmaf(t, fmaf(t, fmaf(t, fmaf(t, 1.061405429f,
               -1.453152027f), 1.421413741f), -0.284496736f), 0.254829592f);
    float e  = __expf(-y * y);
    float er = fmaf(-p, e, 1.0f);                      // erf(|x|/sqrt(2))
    float s  = copysignf(er, x);
    return 0.5f * x * (1.0f + s);
}
__device__ __forceinline__ int clampi(int v, int hi) {
    return v < 0 ? 0 : (v > hi ? hi : v);
}

// ---------------------------------------------------------------------------
// K0m (merged): blocks [0,1024): split A -> AHi/ALo.
//               blocks [1024,1088): gather+split W -> WgHi/WgLo.
// ---------------------------------------------------------------------------
__global__ __launch_bounds__(256) void k0_merged(
        const float* __restrict__ A, const float* __restrict__ W,
        const int* __restrict__ idx, u16* __restrict__ AHi,
        u16* __restrict__ ALo, u16* __restrict__ WgHi,
        u16* __restrict__ WgLo) {
    const int blk = blockIdx.x;
    const int tid = threadIdx.x;
    if (blk < 1024) {                       // ---- splitA ----
        size_t i = ((size_t)blk * 256 + tid) * 8;
        f32x4 a = *(const f32x4*)&A[i];
        f32x4 c = *(const f32x4*)&A[i + 4];
        u16x8 h, l;
        #pragma unroll
        for (int j = 0; j < 4; ++j) {
            u16 hj = f2bf(a[j]); h[j] = hj;     l[j]     = f2bf(a[j] - bf2f(hj));
            u16 hk = f2bf(c[j]); h[j + 4] = hk; l[j + 4] = f2bf(c[j] - bf2f(hk));
        }
        *(u16x8*)&AHi[i] = h;
        *(u16x8*)&ALo[i] = l;
    } else {                                // ---- W prep ----
        const int q  = blk - 1024;          // 0..63
        const int b  = q >> 3;
        const int p0 = (q & 7) * 128;
        __shared__ int idxs[NKIN];
        if (tid < NKIN) idxs[tid] = clampi(idx[b * NKIN + tid], NIN - 1);
        __syncthreads();
        for (int e = tid; e < 128 * NKIN; e += 256) {
            int p = p0 + (e >> 7), k = e & 127;
            float x  = W[p * NIN + idxs[k]];
            u16 hi   = f2bf(x);
            u16 lo   = f2bf(x - bf2f(hi));
            size_t o = (size_t)(b * NPROC + p) * NKIN + k;
            WgHi[o] = hi;
            WgLo[o] = lo;
        }
    }
}

// ---------------------------------------------------------------------------
// K1 (split MFMA + acts_t store, BK=32 four-phase): scores + gelu acts.
// acc = Ahi*Whi + Ahi*Wlo + Alo*Whi. 64x64 tile, 4 waves. LDS pool 20.5KB.
// Epilogue builds transposed tile actsT[p 64][s 64] in the dead pool,
// stores coalesced u16x8 rows to acts_t[b][p][s]. grid 4096, block 256.
// ---------------------------------------------------------------------------
__global__ __launch_bounds__(256) void k1_scores(
        const u16* __restrict__ AHi, const u16* __restrict__ ALo,
        const u16* __restrict__ WgHi, const u16* __restrict__ WgLo,
        float* __restrict__ scores, u16* __restrict__ acts_t) {
    const int lin  = blockIdx.x;
    const int b    = lin & 7;        // XCD via round-robin dispatch
    const int q    = lin >> 3;       // 0..511
    const int pblk = q & 15;         // 0..15
    const int sblk = q >> 4;         // 0..31
    const int p0 = pblk * 64, s0 = sblk * 64;
    const int tid  = threadIdx.x;
    const int lane = tid & 63;
    const int wid  = tid >> 6;
    const int wr   = wid >> 1;       // s quadrant
    const int wc   = wid & 1;        // p quadrant
    const int lr   = lane & 15;
    const int kr   = lane >> 4;

    __shared__ u16  pool[4 * 64 * 40];
    __shared__ float red[2][64];
    char* const pb = (char*)pool;

    f32x4v acc[2][2] = {};

    for (int kc = 0; kc < 4; ++kc) {             // four BK=32 phases
        __syncthreads();
        {   // stage A chunk
            int r = tid >> 2, g = tid & 3;
            size_t src = (size_t)(b * NS + s0 + r) * NKIN + kc * 32 + g * 8;
            u32 off = (u32)r * 80 + (u32)g * 16;
            *(u16x8*)(pb + off)         = *(const u16x8*)&AHi[src];
            *(u16x8*)(pb + 5120 + off)  = *(const u16x8*)&ALo[src];
        }
        {   // stage W chunk
            int pp = tid >> 2, g = tid & 3;
            size_t src = (size_t)(b * NPROC + p0 + pp) * NKIN + kc * 32 + g * 8;
            u32 off = (u32)pp * 80 + (u32)g * 16;
            *(u16x8*)(pb + 10240 + off) = *(const u16x8*)&WgHi[src];
            *(u16x8*)(pb + 15360 + off) = *(const u16x8*)&WgLo[src];
        }
        __syncthreads();

        const u32 kb = (u32)kr * 16;
        bf16x8 ah[2], al[2], wh[2], wl[2];
        #pragma unroll
        for (int m = 0; m < 2; ++m) {
            u32 row = (u32)(wr * 32 + m * 16 + lr);
            u32 off = row * 80 + kb;
            ah[m] = *(const bf16x8*)(pb + off);
            al[m] = *(const bf16x8*)(pb + 5120 + off);
        }
        #pragma unroll
        for (int n = 0; n < 2; ++n) {
            u32 col = (u32)(wc * 32 + n * 16 + lr);
            u32 off = col * 80 + kb;
            wh[n] = *(const bf16x8*)(pb + 10240 + off);
            wl[n] = *(const bf16x8*)(pb + 15360 + off);
        }
        #pragma unroll
        for (int m = 0; m < 2; ++m)
            #pragma unroll
            for (int n = 0; n < 2; ++n) {
                acc[m][n] = __builtin_amdgcn_mfma_f32_16x16x32_bf16(
                    ah[m], wh[n], acc[m][n], 0, 0, 0);
                acc[m][n] = __builtin_amdgcn_mfma_f32_16x16x32_bf16(
                    ah[m], wl[n], acc[m][n], 0, 0, 0);
                acc[m][n] = __builtin_amdgcn_mfma_f32_16x16x32_bf16(
                    al[m], wh[n], acc[m][n], 0, 0, 0);
            }
    }

    // ---- epilogue ----
    __syncthreads();   // pool dead -> actsT[p 64][s 64] swizzled
    float colsum[2] = {0.f, 0.f};
    #pragma unroll
    for (int n = 0; n < 2; ++n)
        #pragma unroll
        for (int m = 0; m < 2; ++m)
            #pragma unroll
            for (int j = 0; j < 4; ++j) {
                float g = gelu_fast(acc[m][n][j]);
                colsum[n] += g;
                if (acts_t) {
                    u32 p = (u32)(wc * 32 + n * 16 + lr);
                    u32 s = (u32)(wr * 32 + m * 16 + kr * 4 + j);
                    u32 off = p * 128 + ((((s >> 3) ^ (p & 7)) & 7) << 4)
                              + (s & 7) * 2;
                    *(u16*)(pb + off) = f2bf(g);
                }
            }
    #pragma unroll
    for (int n = 0; n < 2; ++n) {
        colsum[n] += __shfl_xor(colsum[n], 16, 64);
        colsum[n] += __shfl_xor(colsum[n], 32, 64);
    }
    if (lane < 16) {
        #pragma unroll
        for (int n = 0; n < 2; ++n)
            red[wr][wc * 32 + n * 16 + lane] = colsum[n];
    }
    __syncthreads();
    if (tid < 64)
        scores[(size_t)(sblk * NB + b) * NPROC + p0 + tid] =
            red[0][tid] + red[1][tid];
    if (acts_t) {
        #pragma unroll
        for (int e = tid; e < 512; e += 256) {   // 64 p-rows x 8 s-groups
            int r = e >> 3, g = e & 7;
            u32 off = (u32)r * 128 + ((((u32)g ^ ((u32)r & 7)) & 7) << 4);
            *(u16x8*)&acts_t[(size_t)(b * NPROC + p0 + r) * NS + s0 + g * 8] =
                *(const u16x8*)(pb + off);
        }
    }
}

// ---------------------------------------------------------------------------
// K2: top-k by stable rank count (value desc, index asc == lax.top_k).
// ---------------------------------------------------------------------------
__global__ __launch_bounds__(256) void k2_topk(
        const float* __restrict__ scores, int* __restrict__ topk) {
    const int b  = blockIdx.x;
    const int pc = blockIdx.y;
    __shared__ float sc[NPROC];
    #pragma unroll
    for (int q = 0; q < 4; ++q) {
        int p = q * 256 + threadIdx.x;
        float v = 0.f;
        #pragma unroll
        for (int seg = 0; seg < NSEG; ++seg)
            v += scores[(size_t)(seg * NB + b) * NPROC + p];
        sc[p] = v;
    }
    __syncthreads();
    const int p = pc * 256 + threadIdx.x;
    const float v = sc[p];
    int rank = 0;
    #pragma unroll 4
    for (int jj = 0; jj < NPROC / 4; ++jj) {
        f32x4 s4 = *(const f32x4*)&sc[jj * 4];
        #pragma unroll
        for (int c = 0; c < 4; ++c) {
            int j = jj * 4 + c;
            rank += (s4[c] > v) || (s4[c] == v && j < p);
        }
    }
    if (rank < NKP) topk[b * NKP + rank] = p;
}

// ---------------------------------------------------------------------------
// K4f (fused gather+GEMM): out[b,s,d] = sum_c acts_t[b,tloc[c],s]*PO[tloc[c],d]
// A-staging r=e&63 (32-bank scatter); B-staging kp=e&31 (32-bank writes).
// 128s x 128d tile. grid 1024 (1D), block 256.
// ---------------------------------------------------------------------------
__global__ __launch_bounds__(256) void k4_fused(
        const u16* __restrict__ acts_t, const float* __restrict__ PO,
        const int* __restrict__ topk, float* __restrict__ out) {
    const int lin  = blockIdx.x;
    const int b    = lin & 7;
    const int q    = lin >> 3;
    const int dblk = q & 7;
    const int sblk = q >> 3;
    const int d0 = dblk * 128, s0 = sblk * 128;
    const int tid  = threadIdx.x;
    const int lane = tid & 63;
    const int wid  = tid >> 6;
    const int wr   = wid >> 1;
    const int wc   = wid & 1;

    __shared__ int tloc[NKP];
    __shared__ u16 Alds[128 * 64];   // [s 128][c 64], 128B rows, SW4 swizzle
    __shared__ u16 Blds[128 * 64];   // [d 128][k 64], (n&7) swizzle

    tloc[tid] = clampi(topk[b * NKP + tid], NPROC - 1);

    f32x4v acc[4][4] = {};

    for (int k0 = 0; k0 < NKP; k0 += 64) {
        __syncthreads();
        // ---- A: gather 64 selected acts_t rows; 32-bank scatter ----
        for (int e = tid; e < 1024; e += 256) {
            int r = e & 63, g = e >> 6;   // c-row, s-group
            u16x8 v = *(const u16x8*)&acts_t[
                (size_t)(b * NPROC + tloc[k0 + r]) * NS + s0 + g * 8];
            #pragma unroll
            for (int j = 0; j < 8; ++j) {
                u32 s = (u32)(g * 8 + j);
                u32 sw = (s & 7) ^ ((s >> 3) & 7);
                u32 off = s * 128 + (((((u32)r >> 3) ^ sw) & 7) << 4)
                          + ((u32)r & 7) * 2;
                *(u16*)((char*)Alds + off) = v[j];
            }
        }
        // ---- B: gathered PO rows; kp spans lanes -> 32 banks ----
        for (int e = tid; e < 1024; e += 256) {
            int kp = e & 31, cg = e >> 5;
            f32x4 p0v = *(const f32x4*)&PO[(size_t)tloc[k0 + kp * 2]     * NDM + d0 + cg * 4];
            f32x4 p1v = *(const f32x4*)&PO[(size_t)tloc[k0 + kp * 2 + 1] * NDM + d0 + cg * 4];
            #pragma unroll
            for (int j = 0; j < 4; ++j) {
                int n = cg * 4 + j;
                u32 pack = (u32)f2bf(p0v[j]) | ((u32)f2bf(p1v[j]) << 16);
                u32 byteoff = (u32)n * 128 + (((u32)kp * 4) ^ (((u32)n & 7) << 4));
                *(u32*)((char*)Blds + byteoff) = pack;
            }
        }
        __syncthreads();

        #pragma unroll
        for (int kk = 0; kk < 2; ++kk) {
            const u32 slotk  = (u32)(kk * 4 + (lane >> 4));
            const u32 kbase2 = (u32)(kk * 64 + (lane >> 4) * 16);
            bf16x8 afrag[4], bfrag[4];
            #pragma unroll
            for (int m = 0; m < 4; ++m) {
                u32 row = (u32)(wr * 64 + m * 16 + (lane & 15));   // s
                u32 sw  = (row & 7) ^ ((row >> 3) & 7);
                u32 byteoff = row * 128 + (((slotk ^ sw) & 7) << 4);
                afrag[m] = *(const bf16x8*)((const char*)Alds + byteoff);
            }
            #pragma unroll
            for (int n = 0; n < 4; ++n) {
                u32 col = (u32)(wc * 64 + n * 16 + (lane & 15));
                u32 byteoff = col * 128 + (kbase2 ^ ((col & 7) << 4));
                bfrag[n] = *(const bf16x8*)((const char*)Blds + byteoff);
            }
            #pragma unroll
            for (int m = 0; m < 4; ++m)
                #pragma unroll
                for (int n = 0; n < 4; ++n)
                    acc[m][n] = __builtin_amdgcn_mfma_f32_16x16x32_bf16(
                        afrag[m], bfrag[n], acc[m][n], 0, 0, 0);
        }
    }

    #pragma unroll
    for (int m = 0; m < 4; ++m) {
        const int rbase = s0 + wr * 64 + m * 16 + (lane >> 4) * 4;
        #pragma unroll
        for (int n = 0; n < 4; ++n) {
            const int col = d0 + wc * 64 + n * 16 + (lane & 15);
            #pragma unroll
            for (int j = 0; j < 4; ++j)
                out[(size_t)(b * NS + rbase + j) * NDM + col] = acc[m][n][j];
        }
    }
}

// ---------------------------------------------------------------------------
// K3 (fallback, small ws): prefetch-all MFMA recompute -> sel. grid 1024.
// ---------------------------------------------------------------------------
__global__ __launch_bounds__(256) void k3_selacts(
        const u16* __restrict__ AHi, const u16* __restrict__ WgHi,
        const int* __restrict__ topk, u16* __restrict__ sel) {
    const int lin  = blockIdx.x;
    const int b    = lin & 7;
    const int q    = lin >> 3;
    const int cblk = q & 3;
    const int sblk = q >> 2;
    const int c0g = cblk * 64, s0 = sblk * 64;
    const int tid  = threadIdx.x;
    const int lane = tid & 63;
    const int wid  = tid >> 6;
    const int wr   = wid >> 1;
    const int wc   = wid & 1;
    const int lr   = lane & 15;
    const int kr   = lane >> 4;

    __shared__ int tcol[64];
    if (tid < 64) tcol[tid] = clampi(topk[b * NKP + c0g + tid], NPROC - 1);
    __syncthreads();

    const u16* ap[2];
    const u16* wp[2];
    #pragma unroll
    for (int m = 0; m < 2; ++m)
        ap[m] = &AHi[(size_t)(b * NS + s0 + wr * 32 + m * 16 + lr) * NKIN + kr * 8];
    #pragma unroll
    for (int n = 0; n < 2; ++n)
        wp[n] = &WgHi[(size_t)(b * NPROC + tcol[wc * 32 + n * 16 + lr]) * NKIN + kr * 8];

    bf16x8 af[2][4], bf[2][4];
    #pragma unroll
    for (int ks = 0; ks < 4; ++ks) {
        #pragma unroll
        for (int m = 0; m < 2; ++m) af[m][ks] = *(const bf16x8*)(ap[m] + ks * 32);
        #pragma unroll
        for (int n = 0; n < 2; ++n) bf[n][ks] = *(const bf16x8*)(wp[n] + ks * 32);
    }

    f32x4v acc[2][2] = {};
    #pragma unroll
    for (int ks = 0; ks < 4; ++ks)
        #pragma unroll
        for (int m = 0; m < 2; ++m)
            #pragma unroll
            for (int n = 0; n < 2; ++n)
                acc[m][n] = __builtin_amdgcn_mfma_f32_16x16x32_bf16(
                    af[m][ks], bf[n][ks], acc[m][n], 0, 0, 0);

    #pragma unroll
    for (int m = 0; m < 2; ++m) {
        const int rbase = s0 + wr * 32 + m * 16 + (lane >> 4) * 4;
        #pragma unroll
        for (int n = 0; n < 2; ++n) {
            const int col = c0g + wc * 32 + n * 16 + lr;
            #pragma unroll
            for (int j = 0; j < 4; ++j)
                sel[(size_t)(b * NS + rbase + j) * NKP + col] =
                    f2bf(gelu_fast(acc[m][n][j]));
        }
    }
}

// ---------------------------------------------------------------------------
// K4 (fallback, small ws): sel @ gathered-PO. grid 1024.
// ---------------------------------------------------------------------------
__global__ __launch_bounds__(256) void k4_mfma(
        const u16* __restrict__ sel, const float* __restrict__ PO,
        const int* __restrict__ topk, float* __restrict__ out) {
    const int lin  = blockIdx.x;
    const int b    = lin & 7;
    const int q    = lin >> 3;
    const int dblk = q & 7;
    const int sblk = q >> 3;
    const int d0 = dblk * 128, s0 = sblk * 128;
    const int tid  = threadIdx.x;
    const int lane = tid & 63;
    const int wid  = tid >> 6;
    const int wr   = wid >> 1;
    const int wc   = wid & 1;

    __shared__ int tloc[NKP];
    __shared__ u16 Alds[128 * 64];
    __shared__ u16 Blds[128 * 64];

    tloc[tid] = clampi(topk[b * NKP + tid], NPROC - 1);

    f32x4v acc[4][4] = {};

    for (int k0 = 0; k0 < NKP; k0 += 64) {
        __syncthreads();
        for (int e = tid; e < 1024; e += 256) {
            int r = e >> 3, g = e & 7;
            u16x8 v = *(const u16x8*)&sel[(size_t)(b * NS + s0 + r) * NKP + k0 + g * 8];
            int slot = g ^ (r & 7);
            *(u16x8*)&Alds[r * 64 + slot * 8] = v;
        }
        for (int e = tid; e < 1024; e += 256) {
            int kp = e & 31, cg = e >> 5;
            f32x4 p0v = *(const f32x4*)&PO[(size_t)tloc[k0 + kp * 2]     * NDM + d0 + cg * 4];
            f32x4 p1v = *(const f32x4*)&PO[(size_t)tloc[k0 + kp * 2 + 1] * NDM + d0 + cg * 4];
            #pragma unroll
            for (int j = 0; j < 4; ++j) {
                int n = cg * 4 + j;
                u32 pack = (u32)f2bf(p0v[j]) | ((u32)f2bf(p1v[j]) << 16);
                u32 byteoff = (u32)n * 128 + (((u32)kp * 4) ^ (((u32)n & 7) << 4));
                *(u32*)((char*)Blds + byteoff) = pack;
            }
        }
        __syncthreads();

        #pragma unroll
        for (int kk = 0; kk < 2; ++kk) {
            const u32 kbase2 = (u32)(kk * 64 + (lane >> 4) * 16);
            bf16x8 afrag[4], bfrag[4];
            #pragma unroll
            for (int m = 0; m < 4; ++m) {
                u32 row = (u32)(wr * 64 + m * 16 + (lane & 15));
                u32 byteoff = row * 128 + (kbase2 ^ ((row & 7) << 4));
                afrag[m] = *(const bf16x8*)((const char*)Alds + byteoff);
            }
            #pragma unroll
            for (int n = 0; n < 4; ++n) {
                u32 col = (u32)(wc * 64 + n * 16 + (lane & 15));
                u32 byteoff = col * 128 + (kbase2 ^ ((col & 7) << 4));
                bfrag[n] = *(const bf16x8*)((const char*)Blds + byteoff);
            }
            #pragma unroll
            for (int m = 0; m < 4; ++m)
                #pragma unroll
                for (int n = 0; n < 4; ++n)
                    acc[m][n] = __builtin_amdgcn_mfma_f32_16x16x32_bf16(
                        afrag[m], bfrag[n], acc[m][n], 0, 0, 0);
        }
    }

    #pragma unroll
    for (int m = 0; m < 4; ++m) {
        const int rbase = s0 + wr * 64 + m * 16 + (lane >> 4) * 4;
        #pragma unroll
        for (int n = 0; n < 4; ++n) {
            const int col = d0 + wc * 64 + n * 16 + (lane & 15);
            #pragma unroll
            for (int j = 0; j < 4; ++j)
                out[(size_t)(b * NS + rbase + j) * NDM + col] = acc[m][n][j];
        }
    }
}

// ---------------------------------------------------------------------------
extern "C" void kernel_launch(void* const* d_in, const int* in_sizes, int n_in,
                              void* d_out, int out_size, void* d_ws, size_t ws_size,
                              hipStream_t stream) {
    (void)in_sizes; (void)n_in; (void)out_size;
    const float* A   = (const float*)d_in[0];   // (B,S,K_IN) fp32
    const float* W   = (const float*)d_in[1];   // (N_PROC,N_INPUT) fp32
    const float* PO  = (const float*)d_in[2];   // (N_PROC,D_MODEL) fp32
    const int*   idx = (const int*)d_in[3];     // (B,K_IN) int32
    float* out = (float*)d_out;                 // (B,S,D_MODEL) fp32

    // ws: sel 8388608 | scores 1048576 | topk 8192 | WgHi 2097152 |
    //     WgLo 2097152 | AHi 4194304 | ALo 4194304 | acts_t 33554432
    char* w = (char*)d_ws;
    u16*   sel    = (u16*)w;
    float* scores = (float*)(w + (size_t)8388608);
    int*   topk   = (int*)(w + (size_t)9437184);
    u16*   WgHi   = (u16*)(w + (size_t)9445376);
    u16*   WgLo   = (u16*)(w + (size_t)11542528);
    u16*   AHi    = (u16*)(w + (size_t)13639680);
    u16*   ALo    = (u16*)(w + (size_t)17833984);
    u16*   acts_t = (u16*)(w + (size_t)22028288);   // [B][NPROC][NS] bf16
    const bool big = ws_size >= (size_t)22028288 + 33554432;   // 53 MB

    k0_merged<<<1024 + 64, 256, 0, stream>>>(A, W, idx, AHi, ALo, WgHi, WgLo);
    k1_scores<<<4096, 256, 0, stream>>>(AHi, ALo, WgHi, WgLo, scores,
                                        big ? acts_t : (u16*)nullptr);
    k2_topk<<<dim3(NB, 4), 256, 0, stream>>>(scores, topk);
    if (big) {
        k4_fused<<<1024, 256, 0, stream>>>(acts_t, PO, topk, out);
    } else {
        k3_selacts<<<1024, 256, 0, stream>>>(AHi, WgHi, topk, sel);
        k4_mfma<<<1024, 256, 0, stream>>>(sel, PO, topk, out);
    }
}